// Round 3
// baseline (667.446 us; speedup 1.0000x reference)
//
#include <hip/hip_runtime.h>
#include <float.h>

#define DIM      512
#define NCLS     21
#define MARGIN_V 5.0f
#define NWAVES   8                  // waves per block; wave w owns d-slice [w*64, w*64+64)
#define DSLICE   (DIM / NWAVES)     // 64
#define RPL      4                  // rows per lane  -> each center b128 feeds 16 FMAs/lane
#define ROWS_PB  (64 * RPL)         // 256 rows per block
#define DC       8                  // d-floats staged per stage
#define NSTAGE   (DSLICE / DC)      // 8
#define CLDSF    (NCLS * DIM)       // 10752 floats: full centers table (43008 B)
#define TILEF    (ROWS_PB * DC)     // 2048 floats per wave tile (8192 B)
#define LDSF     (CLDSF + NWAVES * TILEF)   // 27136 floats = 108544 B -> 1 block/CU
#define SST      (RPL * NCLS + 1)   // 85: odd combine stride -> conflict-free b32

// Kernel 1: halfc2[c] = 0.5 * ||centers[c]||^2  -> d_ws
__global__ __launch_bounds__(64)
void center_norm_kernel(const float* __restrict__ centers,
                        float* __restrict__ halfc2) {
    const int c = blockIdx.x;
    const int t = threadIdx.x;
    float s = 0.f;
#pragma unroll
    for (int i = 0; i < DIM / 64; ++i) {
        float v = centers[c * DIM + i * 64 + t];
        s = fmaf(v, v, s);
    }
#pragma unroll
    for (int off = 32; off > 0; off >>= 1)
        s += __shfl_down(s, off, 64);
    if (t == 0) halfc2[c] = 0.5f * s;
}

// Kernel 2: 8 waves/block; wave w computes partial dots over its 64-d slice for
// 256 rows, 4 rows per lane. Center ds_read_b128 broadcasts are amortized over
// 4 rows (DS:FMA ratio cut 4x vs round 2 -- the DS pipe was the bottleneck).
// Feature tiles wave-private, [jj-plane][row] layout -> contiguous b128 reads.
// Main loop barrier-free; cross-wave combine tree at the end.
__global__ __launch_bounds__(512, 2)
void tcl_main_kernel(const float* __restrict__ feat,
                     const float* __restrict__ centers,
                     const int* __restrict__ labels,
                     const float* __restrict__ halfc2,
                     float* __restrict__ out) {
    __shared__ float lds[LDSF];

    const int tid  = threadIdx.x;
    const int w    = __builtin_amdgcn_readfirstlane(tid >> 6);  // uniform wave id
    const int t    = tid & 63;
    const int row0 = blockIdx.x * ROWS_PB;

    float acc[RPL][NCLS];
#pragma unroll
    for (int r = 0; r < RPL; ++r)
#pragma unroll
        for (int c = 0; c < NCLS; ++c) acc[r][c] = 0.f;

    const float4* fbase = reinterpret_cast<const float4*>(feat);
    // Per stage this wave loads 256 rows x 8 floats = 512 float4, 8 per lane.
    // Load i: f = i*64 + t -> row = f>>1 (in [i*32, i*32+32)), j = f&1.
    // Lane pairs read adjacent float4s of one row: 32B chunks, consecutive
    // stages complete each 64B line -> full line consumption via L1.
    float4 pre[8];
#pragma unroll
    for (int i = 0; i < 8; ++i) {
        int f = i * 64 + t;
        pre[i] = fbase[(size_t)(row0 + (f >> 1)) * (DIM / 4)
                       + (size_t)w * (DSLICE / 4) + (f & 1)];   // stage 0
    }
    __builtin_amdgcn_sched_barrier(0);

    // stage full centers table into LDS (block-cooperative, float4)
    {
        const float4* c4 = reinterpret_cast<const float4*>(centers);
        float4* l4 = reinterpret_cast<float4*>(lds);
#pragma unroll
        for (int i = 0; i < (CLDSF / 4 + 511) / 512; ++i) {
            int idx = i * 512 + tid;
            if (idx < CLDSF / 4) l4[idx] = c4[idx];
        }
    }

    float* mytile = &lds[CLDSF + w * TILEF];

    __syncthreads();   // centers ready; main loop below is barrier-free

#pragma unroll 1
    for (int s = 0; s < NSTAGE; ++s) {
        // write prefetched stage into wave-private tile: plane j, row-major f4
#pragma unroll
        for (int i = 0; i < 8; ++i) {
            int f = i * 64 + t;
            *reinterpret_cast<float4*>(
                &mytile[(f & 1) * (ROWS_PB * 4) + (f >> 1) * 4]) = pre[i];
        }
        // issue next stage's global loads; pin them here
        if (s + 1 < NSTAGE) {
#pragma unroll
            for (int i = 0; i < 8; ++i) {
                int f = i * 64 + t;
                pre[i] = fbase[(size_t)(row0 + (f >> 1)) * (DIM / 4)
                               + (size_t)w * (DSLICE / 4)
                               + (size_t)(s + 1) * (DC / 4) + (f & 1)];
            }
        }
        __builtin_amdgcn_sched_barrier(0);

        // compute: lane owns rows t, t+64, t+128, t+192
#pragma unroll
        for (int j2 = 0; j2 < 2; ++j2) {
            float4 fv[RPL];
#pragma unroll
            for (int r = 0; r < RPL; ++r)
                fv[r] = *reinterpret_cast<const float4*>(
                    &mytile[j2 * (ROWS_PB * 4) + (t + r * 64) * 4]);
            const int dbase = w * DSLICE + s * DC + j2 * 4;
            // 3 chunks of 7 classes bound center-VGPR liveness (28 regs)
#pragma unroll
            for (int ch = 0; ch < 3; ++ch) {
                float4 cv[7];
#pragma unroll
                for (int k = 0; k < 7; ++k)
                    cv[k] = *reinterpret_cast<const float4*>(
                        &lds[(ch * 7 + k) * DIM + dbase]);
#pragma unroll
                for (int k = 0; k < 7; ++k) {
                    const int c = ch * 7 + k;
#pragma unroll
                    for (int r = 0; r < RPL; ++r) {
                        acc[r][c] = fmaf(fv[r].x, cv[k].x,
                                     fmaf(fv[r].y, cv[k].y,
                                      fmaf(fv[r].z, cv[k].z,
                                       fmaf(fv[r].w, cv[k].w, acc[r][c]))));
                    }
                }
            }
        }
    }

    // ---- cross-wave combine: 8 -> 4 -> 2 -> 1 (d-slice partial sums) ----
    float* scratch = lds;   // reuse: 4 slots x 64 lanes x 85 = 21760 f <= LDSF
    __syncthreads();
    if (w >= 4) {
        float* p = &scratch[((w - 4) * 64 + t) * SST];
#pragma unroll
        for (int r = 0; r < RPL; ++r)
#pragma unroll
            for (int c = 0; c < NCLS; ++c) p[r * NCLS + c] = acc[r][c];
    }
    __syncthreads();
    if (w < 4) {
        const float* p = &scratch[(w * 64 + t) * SST];
#pragma unroll
        for (int r = 0; r < RPL; ++r)
#pragma unroll
            for (int c = 0; c < NCLS; ++c) acc[r][c] += p[r * NCLS + c];
    }
    __syncthreads();
    if (w == 2 || w == 3) {
        float* p = &scratch[((w - 2) * 64 + t) * SST];
#pragma unroll
        for (int r = 0; r < RPL; ++r)
#pragma unroll
            for (int c = 0; c < NCLS; ++c) p[r * NCLS + c] = acc[r][c];
    }
    __syncthreads();
    if (w < 2) {
        const float* p = &scratch[(w * 64 + t) * SST];
#pragma unroll
        for (int r = 0; r < RPL; ++r)
#pragma unroll
            for (int c = 0; c < NCLS; ++c) acc[r][c] += p[r * NCLS + c];
    }
    __syncthreads();
    if (w == 1) {
        float* p = &scratch[t * SST];
#pragma unroll
        for (int r = 0; r < RPL; ++r)
#pragma unroll
            for (int c = 0; c < NCLS; ++c) p[r * NCLS + c] = acc[r][c];
    }
    __syncthreads();
    if (w == 0) {
        const float* p = &scratch[t * SST];
        float vsum = 0.f;
#pragma unroll
        for (int r = 0; r < RPL; ++r) {
            const int lab = labels[row0 + t + r * 64];
            float pos = 0.f, neg = FLT_MAX;
#pragma unroll
            for (int c = 0; c < NCLS; ++c) {
                float e = halfc2[c] - (acc[r][c] + p[r * NCLS + c]);
                pos = (c == lab) ? e : pos;
                neg = (c == lab) ? neg : fminf(neg, e);
            }
            vsum += fmaxf(pos + MARGIN_V - neg, 0.f);
        }
#pragma unroll
        for (int off = 32; off > 0; off >>= 1)
            vsum += __shfl_down(vsum, off, 64);
        if (t == 0) atomicAdd(out, vsum * (1.0f / 65536.f));
    }
}

extern "C" void kernel_launch(void* const* d_in, const int* in_sizes, int n_in,
                              void* d_out, int out_size, void* d_ws, size_t ws_size,
                              hipStream_t stream) {
    const float* feat    = (const float*)d_in[0];   // (65536, 512) fp32
    const float* centers = (const float*)d_in[1];   // (21, 512) fp32
    const int*   labels  = (const int*)d_in[2];     // (65536,) int
    float* out    = (float*)d_out;                  // scalar loss
    float* halfc2 = (float*)d_ws;                   // 21 floats scratch

    hipMemsetAsync(d_out, 0, (size_t)out_size * sizeof(float), stream);
    center_norm_kernel<<<NCLS, 64, 0, stream>>>(centers, halfc2);

    const int nblocks = 65536 / ROWS_PB;            // 256 blocks x 8 waves = 2048 waves
    tcl_main_kernel<<<nblocks, 512, 0, stream>>>(feat, centers, labels, halfc2, out);
}

// Round 4
// 313.412 us; speedup vs baseline: 2.1296x; 2.1296x over previous
//
#include <hip/hip_runtime.h>
#include <float.h>

#define DIM      512
#define NCLS     21
#define MARGIN_V 5.0f
#define NWAVES   8                  // waves per block; wave w owns d-slice [w*64, w*64+64)
#define DSLICE   (DIM / NWAVES)     // 64
#define RPL      4                  // rows per lane -> center b128 amortized over 16 FMAs/lane
#define ROWS_PB  (64 * RPL)         // 256 rows per block; grid 256 = exactly 1 block/CU
#define DC       4                  // d-floats staged per stage (1 float4 per row)
#define NSTAGE   (DSLICE / DC)      // 16
#define CLDSF    (NCLS * DIM)       // 10752 floats: centers table (43008 B)
#define TILEF    (ROWS_PB * DC)     // 1024 floats per wave tile (4096 B)
#define MAINF    (CLDSF + NWAVES * TILEF)   // 18944 floats main-phase LDS
#define SLOTF    (64 * NCLS * 4)    // 5376 floats per combine slot (21 f4 per lane, odd f4 stride)
#define LDSF     (4 * SLOTF)        // 21504 floats = 86016 B (combine phase needs more than main)

// Kernel 1: halfc2[c] = 0.5 * ||centers[c]||^2  -> d_ws
__global__ __launch_bounds__(64)
void center_norm_kernel(const float* __restrict__ centers,
                        float* __restrict__ halfc2) {
    const int c = blockIdx.x;
    const int t = threadIdx.x;
    float s = 0.f;
#pragma unroll
    for (int i = 0; i < DIM / 64; ++i) {
        float v = centers[c * DIM + i * 64 + t];
        s = fmaf(v, v, s);
    }
#pragma unroll
    for (int off = 32; off > 0; off >>= 1)
        s += __shfl_down(s, off, 64);
    if (t == 0) halfc2[c] = 0.5f * s;
}

// Kernel 2: 8 waves/block; wave w does partial dots over its 64-d slice for 256
// rows, 4 rows per lane (acc[4][21] = 84 VGPRs). Center ds_read_b128 broadcasts
// amortized over 4 rows (DS pipe was the round-2 bottleneck). launch_bounds
// (512, 1): min 1 BLOCK/CU (CUDA semantics on this toolchain) -> VGPR cap 256,
// no spills (round 3 died on acc spills at cap 128).
__global__ __launch_bounds__(512, 1)
void tcl_main_kernel(const float* __restrict__ feat,
                     const float* __restrict__ centers,
                     const int* __restrict__ labels,
                     const float* __restrict__ halfc2,
                     float* __restrict__ out) {
    __shared__ float lds[LDSF];

    const int tid  = threadIdx.x;
    const int w    = __builtin_amdgcn_readfirstlane(tid >> 6);  // uniform wave id
    const int t    = tid & 63;
    const int row0 = blockIdx.x * ROWS_PB;

    // preload labels early (only wave 0 needs them; loads fly under main loop)
    int labv[RPL];
    if (w == 0) {
#pragma unroll
        for (int r = 0; r < RPL; ++r) labv[r] = labels[row0 + t + r * 64];
    }

    float acc[RPL][NCLS];
#pragma unroll
    for (int r = 0; r < RPL; ++r)
#pragma unroll
        for (int c = 0; c < NCLS; ++c) acc[r][c] = 0.f;

    const float4* fbase = reinterpret_cast<const float4*>(feat);
    // Per stage this wave loads 256 rows x 1 float4; lane t handles rows i*64+t.
    // Same 64B line feeds 4 consecutive stages (L1-resident, 16KB working set).
    float4 pre[4];
#pragma unroll
    for (int i = 0; i < 4; ++i)
        pre[i] = fbase[(size_t)(row0 + i * 64 + t) * (DIM / 4)
                       + (size_t)w * (DSLICE / 4)];              // stage 0
    __builtin_amdgcn_sched_barrier(0);

    // stage full centers table into LDS (block-cooperative, float4)
    {
        const float4* c4 = reinterpret_cast<const float4*>(centers);
        float4* l4 = reinterpret_cast<float4*>(lds);
#pragma unroll
        for (int i = 0; i < (CLDSF / 4 + 511) / 512; ++i) {
            int idx = i * 512 + tid;
            if (idx < CLDSF / 4) l4[idx] = c4[idx];
        }
    }

    float* mytile = &lds[CLDSF + w * TILEF];

    __syncthreads();   // centers ready; main loop below is barrier-free

#pragma unroll 1
    for (int s = 0; s < NSTAGE; ++s) {
        // write prefetched stage into wave-private tile (dense row-major f4:
        // 64 lanes x 16B contiguous = optimal 8-cycle b128 pattern)
#pragma unroll
        for (int i = 0; i < 4; ++i)
            *reinterpret_cast<float4*>(&mytile[(i * 64 + t) * DC]) = pre[i];
        // issue next stage's global loads; pin them here
        if (s + 1 < NSTAGE) {
#pragma unroll
            for (int i = 0; i < 4; ++i)
                pre[i] = fbase[(size_t)(row0 + i * 64 + t) * (DIM / 4)
                               + (size_t)w * (DSLICE / 4) + (s + 1)];
        }
        __builtin_amdgcn_sched_barrier(0);

        // compute: lane owns rows t, t+64, t+128, t+192
        float4 fv[RPL];
#pragma unroll
        for (int r = 0; r < RPL; ++r)
            fv[r] = *reinterpret_cast<const float4*>(&mytile[(t + r * 64) * DC]);
        const int dbase = w * DSLICE + s * DC;
        // 3 chunks of 7 classes bound center-VGPR liveness (28 regs)
#pragma unroll
        for (int ch = 0; ch < 3; ++ch) {
            float4 cv[7];
#pragma unroll
            for (int k = 0; k < 7; ++k)
                cv[k] = *reinterpret_cast<const float4*>(
                    &lds[(ch * 7 + k) * DIM + dbase]);
#pragma unroll
            for (int k = 0; k < 7; ++k) {
                const int c = ch * 7 + k;
#pragma unroll
                for (int r = 0; r < RPL; ++r) {
                    acc[r][c] = fmaf(fv[r].x, cv[k].x,
                                 fmaf(fv[r].y, cv[k].y,
                                  fmaf(fv[r].z, cv[k].z,
                                   fmaf(fv[r].w, cv[k].w, acc[r][c]))));
                }
            }
        }
    }

    // ---- cross-wave combine: 8 -> 4 -> 2 -> 1, float4, odd-f4-stride (21) ----
    float* scratch = lds;
    __syncthreads();
    if (w >= 4) {
        float4* p4 = reinterpret_cast<float4*>(
            &scratch[(size_t)(w - 4) * SLOTF + t * (NCLS * 4)]);
#pragma unroll
        for (int c = 0; c < NCLS; ++c)
            p4[c] = make_float4(acc[0][c], acc[1][c], acc[2][c], acc[3][c]);
    }
    __syncthreads();
    if (w < 4) {
        const float4* p4 = reinterpret_cast<const float4*>(
            &scratch[(size_t)w * SLOTF + t * (NCLS * 4)]);
#pragma unroll
        for (int c = 0; c < NCLS; ++c) {
            float4 q = p4[c];
            acc[0][c] += q.x; acc[1][c] += q.y; acc[2][c] += q.z; acc[3][c] += q.w;
        }
    }
    __syncthreads();
    if (w == 2 || w == 3) {
        float4* p4 = reinterpret_cast<float4*>(
            &scratch[(size_t)(w - 2) * SLOTF + t * (NCLS * 4)]);
#pragma unroll
        for (int c = 0; c < NCLS; ++c)
            p4[c] = make_float4(acc[0][c], acc[1][c], acc[2][c], acc[3][c]);
    }
    __syncthreads();
    if (w < 2) {
        const float4* p4 = reinterpret_cast<const float4*>(
            &scratch[(size_t)w * SLOTF + t * (NCLS * 4)]);
#pragma unroll
        for (int c = 0; c < NCLS; ++c) {
            float4 q = p4[c];
            acc[0][c] += q.x; acc[1][c] += q.y; acc[2][c] += q.z; acc[3][c] += q.w;
        }
    }
    __syncthreads();
    if (w == 1) {
        float4* p4 = reinterpret_cast<float4*>(&scratch[t * (NCLS * 4)]);
#pragma unroll
        for (int c = 0; c < NCLS; ++c)
            p4[c] = make_float4(acc[0][c], acc[1][c], acc[2][c], acc[3][c]);
    }
    __syncthreads();
    if (w == 0) {
        const float4* p4 = reinterpret_cast<const float4*>(&scratch[t * (NCLS * 4)]);
#pragma unroll
        for (int c = 0; c < NCLS; ++c) {
            float4 q = p4[c];
            acc[0][c] += q.x; acc[1][c] += q.y; acc[2][c] += q.z; acc[3][c] += q.w;
        }
        float vsum = 0.f;
#pragma unroll
        for (int r = 0; r < RPL; ++r) {
            const int lab = labv[r];
            float pos = 0.f, neg = FLT_MAX;
#pragma unroll
            for (int c = 0; c < NCLS; ++c) {
                float e = halfc2[c] - acc[r][c];
                pos = (c == lab) ? e : pos;
                neg = (c == lab) ? neg : fminf(neg, e);
            }
            vsum += fmaxf(pos + MARGIN_V - neg, 0.f);
        }
#pragma unroll
        for (int off = 32; off > 0; off >>= 1)
            vsum += __shfl_down(vsum, off, 64);
        if (t == 0) atomicAdd(out, vsum * (1.0f / 65536.f));
    }
}

extern "C" void kernel_launch(void* const* d_in, const int* in_sizes, int n_in,
                              void* d_out, int out_size, void* d_ws, size_t ws_size,
                              hipStream_t stream) {
    const float* feat    = (const float*)d_in[0];   // (65536, 512) fp32
    const float* centers = (const float*)d_in[1];   // (21, 512) fp32
    const int*   labels  = (const int*)d_in[2];     // (65536,) int
    float* out    = (float*)d_out;                  // scalar loss
    float* halfc2 = (float*)d_ws;                   // 21 floats scratch

    hipMemsetAsync(d_out, 0, (size_t)out_size * sizeof(float), stream);
    center_norm_kernel<<<NCLS, 64, 0, stream>>>(centers, halfc2);

    const int nblocks = 65536 / ROWS_PB;            // 256 blocks x 8 waves = 1 block/CU
    tcl_main_kernel<<<nblocks, 512, 0, stream>>>(feat, centers, labels, halfc2, out);
}